// Round 11
// baseline (568.188 us; speedup 1.0000x reference)
//
#include <hip/hip_runtime.h>
#include <hip/hip_bf16.h>
#include <stdint.h>

#define AS1 __attribute__((address_space(1)))
#define AS3 __attribute__((address_space(3)))

typedef __attribute__((ext_vector_type(8))) __bf16 bf16x8;
typedef __attribute__((ext_vector_type(4))) float f32x4;
typedef unsigned short u16;
typedef __attribute__((ext_vector_type(8))) unsigned short u16x8;

// ---- problem sizes (fixed for this module) ----
#define B_    8
#define S_    512
#define NH_   12
#define HD_   768
#define NHD_  (NH_*HD_)     // 9216
#define D3_   (3*NHD_)      // 27648
#define QKLD_ (2*NHD_)      // 18432: natural Q|K layout leading dim
#define QK_SCALE 0.03608439182435161f   // 1/sqrt(768)

__device__ __forceinline__ u16 f2bf(float x) {
  union { float f; unsigned u; } a; a.f = x;
  unsigned r = a.u + 0x7fffu + ((a.u >> 16) & 1u);   // RNE
  return (u16)(r >> 16);
}
__device__ __forceinline__ float bf2f(u16 x) {
  union { unsigned u; float f; } a; a.u = ((unsigned)x) << 16; return a.f;
}
// packed RNE f32x2 -> bf16x2 (one VALU inst per pair)
__device__ __forceinline__ uint2 pack4(float a, float b, float c, float d) {
  uint2 r;
  asm("v_cvt_pk_bf16_f32 %0, %1, %2" : "=v"(r.x) : "v"(a), "v"(b));
  asm("v_cvt_pk_bf16_f32 %0, %1, %2" : "=v"(r.y) : "v"(c), "v"(d));
  return r;
}

__device__ __forceinline__ void gload16(const void* g, void* l) {
  // async global->LDS; LDS dest = wave-uniform base + lane*16, global src per-lane
  __builtin_amdgcn_global_load_lds((const AS1 void*)g, (AS3 void*)l, 16, 0, 0);
}

// ============================================================================
// 128x128 GEMM, 256 threads (2x2 waves), BK=32 DOUBLE-BUFFERED in 32KB LDS
// (A[2] 8KB + B[2] 8KB) -> occupancy stays 5 blocks/CU AND 1-deep prefetch:
//   stage(0); loop t: { stage(t+1) -> vmcnt(4) [drains stage(t) only] ->
//                       barrier -> 8x ds_read_b128 + 16 MFMA -> barrier }
// Ledger: at wait, outstanding = stage(t):4 + stage(t+1):4 -> vmcnt(4) drains
// exactly stage(t); stage(t+1) hides under compute(t). Tail: vmcnt(0).
// WAR: stage(t+1) overwrites buf((t+1)&1), last read by compute(t-1) which is
// sealed by iter t-1's closing barrier (program order: barrier -> stage). Safe.
// Swizzle for 64B rows (verified 0 conflicts, round 4): logical col16 c of row
// r at phys c^((r>>1)&3); staging pre-swizzles source col (lane&3)^((lane>>3)&3)
// [row = w*32+g*16+(lane>>2) -> (r>>1)&3 = (lane>>3)&3]; read phys col16 =
// (lane>>4)^((lane>>1)&3) [row&15 = lane&15].
// OPERAND-SWAPPED MFMA (round 9): mfma(bv, av) -> D quad = 4 consecutive
// N-cols for fixed M-row. Compile-time LDA/LDB/K.
// Grid mappings (round 10, proven):
//  MODE 0: 2-D grid, n fastest (A-panel L2-hot across 216 consecutive blocks)
//  MODE 1/2: all blocks of a head z on one XCD;  MODE 3: 2 XCDs per K-chunk
// MODE 0: QKV proj -> Q|K natural [row][18432] uint2; V -> Vt (z,h,s)
// MODE 1: scores -> S bf16 [z][row][col] * QK_SCALE (uint2)
// MODE 2: AV     -> H at (zb*512+row)*18432 + zn*768 + col (uint2)
// MODE 3: out-proj split-K partial -> fp32 Part[z][row][col] (float4)
// ============================================================================
struct GP {
  const u16* A;   // + zb*sAb + zn*sAn
  const u16* B;   // + zb*sBb + zn*sBn   (C = A * B^T)
  long sAb, sAn, sBb, sBn;
  void* o0; void* o2;
  const float* bias;
  int mMask, mShift, zPerX;
};

template<int MODE, int LDA, int LDB, int KK>
__global__ __launch_bounds__(256)
void gemm_bt(GP p) {
  __shared__ __align__(16) char smem[32768];   // A0|A1|B0|B1, 8KB each
  const int tid  = threadIdx.x;
  const int wave = tid >> 6, lane = tid & 63;
  const int wr = wave >> 1, wc = wave & 1;     // 2x2 waves, 64x64 each

  // ---- grid mapping ----
  int m_idx, n_idx, z;
  if constexpr (MODE == 0) {
    m_idx = blockIdx.y; n_idx = blockIdx.x; z = 0;   // n fastest
  } else {
    const int bid = blockIdx.x;
    const int xcd = bid & 7, loc = bid >> 3;
    if constexpr (MODE == 1) {
      int inner;
      if (p.zPerX) { inner = loc & 15; z = xcd * p.zPerX + (loc >> 4); }
      else         { inner = bid & 15; z = bid >> 4; }
      m_idx = inner >> 2; n_idx = inner & 3;
    } else if constexpr (MODE == 2) {
      int inner;
      if (p.zPerX) { inner = loc % 24; z = xcd * p.zPerX + loc / 24; }
      else         { inner = bid % 24; z = bid / 24; }
      m_idx = inner / 6; n_idx = inner - (inner / 6) * 6;
    } else {
      m_idx = loc & p.mMask;
      n_idx = (xcd & 1) * 3 + (loc >> p.mShift);   // 0..5
      z = xcd >> 1;                                 // K-chunk 0..3
    }
  }
  const int bm0 = m_idx * 128, bn0 = n_idx * 128;
  const int zb  = z / NH_, zn = z - zb * NH_;

  const u16* A  = p.A + zb * p.sAb + zn * p.sAn;
  const u16* Bm = p.B + zb * p.sBb + zn * p.sBn;

  f32x4 acc[4][4];
  const f32x4 zero4 = {0.f, 0.f, 0.f, 0.f};
#pragma unroll
  for (int i = 0; i < 4; ++i)
#pragma unroll
    for (int j = 0; j < 4; ++j) acc[i][j] = zero4;

  // staging: wave w, gload g in {0,1}: rows w*32+g*16+(lane>>2), slot lane&3
  const int scolsw = ((lane & 3) ^ ((lane >> 3) & 3)) * 8;   // elements
  const int srow = wave * 32 + (lane >> 2);
  const u16* gA = A  + (size_t)(bm0 + srow) * LDA + scolsw;
  const u16* gB = Bm + (size_t)(bn0 + srow) * LDB + scolsw;
  const int stw = wave * 2048;

  char* ldsA = smem;            // + (t&1)*8192
  char* ldsB = smem + 16384;

  auto stage = [&](int t) {
    char* da = ldsA + (t & 1) * 8192 + stw;
    char* db = ldsB + (t & 1) * 8192 + stw;
    const u16* sa = gA + t * 32;
    const u16* sb = gB + t * 32;
    gload16(sa,                     da);
    gload16(sa + (size_t)16 * LDA,  da + 1024);
    gload16(sb,                     db);
    gload16(sb + (size_t)16 * LDB,  db + 1024);
  };

  // fragment reads: [128 rows][64B], frag row = base + i*16 + (lane&15)
  const int aRow = (wr * 64 + (lane & 15)) * 64;
  const int bRow = (wc * 64 + (lane & 15)) * 64;
  const int cOff = (((lane >> 4)) ^ ((lane >> 1) & 3)) << 4;

  constexpr int NT = KK / 32;
  stage(0);
  for (int t = 0; t < NT; ++t) {
    if (t + 1 < NT) {
      stage(t + 1);
      asm volatile("s_waitcnt vmcnt(4)" ::: "memory");
    } else {
      asm volatile("s_waitcnt vmcnt(0)" ::: "memory");
    }
    __builtin_amdgcn_s_barrier();
    asm volatile("" ::: "memory");

    const char* bA = ldsA + (t & 1) * 8192;
    const char* bB = ldsB + (t & 1) * 8192;
    bf16x8 av[4], bv[4];
#pragma unroll
    for (int i = 0; i < 4; ++i)
      av[i] = *(const bf16x8*)(bA + aRow + i * 1024 + cOff);
#pragma unroll
    for (int j = 0; j < 4; ++j)
      bv[j] = *(const bf16x8*)(bB + bRow + j * 1024 + cOff);
    // swapped operands: D quad = consecutive n, lane&15 = m
#pragma unroll
    for (int i = 0; i < 4; ++i)
#pragma unroll
      for (int j = 0; j < 4; ++j)
        acc[i][j] = __builtin_amdgcn_mfma_f32_16x16x32_bf16(bv[j], av[i], acc[i][j], 0, 0, 0);

    asm volatile("" ::: "memory");
    __builtin_amdgcn_s_barrier();
    asm volatile("" ::: "memory");
  }

  // epilogue (swapped layout): m = bm0+wr*64+i*16+(lane&15),
  //                            n = bn0+wc*64+j*16+(lane>>4)*4 + r
  const int mBase = bm0 + wr*64 + (lane & 15);
  const int nBase = bn0 + wc*64 + ((lane >> 4) << 2);
#pragma unroll
  for (int i = 0; i < 4; ++i) {
    const int m = mBase + i*16;
#pragma unroll
    for (int j = 0; j < 4; ++j) {
      const int n = nBase + j*16;
      const f32x4 v = acc[i][j];
      if constexpr (MODE == 0) {
        const float4 b4 = *(const float4*)(p.bias + n);
        if (bn0 < QKLD_) {
          *(uint2*)((u16*)p.o0 + (long)m * QKLD_ + n) =
              pack4(v[0]+b4.x, v[1]+b4.y, v[2]+b4.z, v[3]+b4.w);
        } else {
          const int vcol = n - QKLD_;
          const int nh = vcol / HD_;
          const int h  = vcol - nh * HD_;
          u16* vb = (u16*)p.o2 + (long)((m >> 9) * NH_ + nh) * (S_*HD_)
                    + (long)h * S_ + (m & 511);
          vb[0]    = f2bf(v[0]+b4.x);
          vb[512]  = f2bf(v[1]+b4.y);
          vb[1024] = f2bf(v[2]+b4.z);
          vb[1536] = f2bf(v[3]+b4.w);
        }
      } else if constexpr (MODE == 1) {
        *(uint2*)((u16*)p.o0 + (long)z*S_*S_ + (long)m*S_ + n) =
            pack4(v[0]*QK_SCALE, v[1]*QK_SCALE, v[2]*QK_SCALE, v[3]*QK_SCALE);
      } else if constexpr (MODE == 2) {
        *(uint2*)((u16*)p.o0 + (long)(zb*S_ + m)*QKLD_ + zn*HD_ + n) =
            pack4(v[0], v[1], v[2], v[3]);
      } else {
        const long rowsTot = (long)(p.mMask + 1) * 128;
        *(float4*)((float*)p.o0 + ((long)z * rowsTot + m) * HD_ + n) =
            *(const float4*)&v;
      }
    }
  }
}

// one wave per row (512 cols, bf16, IN-PLACE): +mask, softmax
__global__ __launch_bounds__(256)
void softmax_rows(u16* __restrict__ SP, const float* __restrict__ maskc) {
  const int wave = threadIdx.x >> 6, lane = threadIdx.x & 63;
  const int rid = blockIdx.x * 4 + wave;
  const int z = rid >> 9;
  const int b = z / NH_;
  const u16x8 sv = *(const u16x8*)(SP + (size_t)rid * S_ + lane*8);
  const float* mrow = maskc + (size_t)b * S_;
  float vals[8];
  float m = -3.4e38f;
#pragma unroll
  for (int j = 0; j < 8; ++j) {
    vals[j] = bf2f(sv[j]) + mrow[lane*8 + j];
    m = fmaxf(m, vals[j]);
  }
#pragma unroll
  for (int o = 32; o > 0; o >>= 1) m = fmaxf(m, __shfl_xor(m, o));
  float sum = 0.f;
#pragma unroll
  for (int j = 0; j < 8; ++j) { vals[j] = __expf(vals[j] - m); sum += vals[j]; }
#pragma unroll
  for (int o = 32; o > 0; o >>= 1) sum += __shfl_xor(sum, o);
  const float inv = 1.0f / sum;
  u16x8 pv;
#pragma unroll
  for (int j = 0; j < 8; ++j) pv[j] = f2bf(vals[j] * inv);
  *(u16x8*)(SP + (size_t)rid * S_ + lane*8) = pv;
}

__global__ __launch_bounds__(256)
void cvt_bf16(const float4* __restrict__ in, ushort4* __restrict__ out, int n4) {
  const int i = blockIdx.x * 256 + threadIdx.x;
  if (i >= n4) return;
  const float4 v = in[i];
  ushort4 o;
  o.x = f2bf(v.x); o.y = f2bf(v.y); o.z = f2bf(v.z); o.w = f2bf(v.w);
  out[i] = o;
}

// out = sum of 4 fp32 partials + bias; n4 = rows_c*768/4 (float4 units)
__global__ __launch_bounds__(256)
void combine_out(const float4* __restrict__ part, const float* __restrict__ b,
                 float4* __restrict__ out, int n4) {
  const int i = blockIdx.x * 256 + threadIdx.x;
  if (i >= n4) return;
  const float4 a0 = part[i];
  const float4 a1 = part[i + (size_t)n4];
  const float4 a2 = part[i + (size_t)2*n4];
  const float4 a3 = part[i + (size_t)3*n4];
  const int c = (i * 4) % HD_;
  float4 o;
  o.x = a0.x + a1.x + a2.x + a3.x + b[c];
  o.y = a0.y + a1.y + a2.y + a3.y + b[c+1];
  o.z = a0.z + a1.z + a2.z + a3.z + b[c+2];
  o.w = a0.w + a1.w + a2.w + a3.w + b[c+3];
  out[i] = o;
}

extern "C" void kernel_launch(void* const* d_in, const int* in_sizes, int n_in,
                              void* d_out, int out_size, void* d_ws, size_t ws_size,
                              hipStream_t stream) {
  const float* x     = (const float*)d_in[0];
  const float* mask  = (const float*)d_in[1];
  const float* w_qkv = (const float*)d_in[2];
  const float* b_qkv = (const float*)d_in[3];
  const float* w_o   = (const float*)d_in[4];
  const float* b_o   = (const float*)d_in[5];
  float* out = (float*)d_out;

  // workspace (same footprint as rounds 2-10):
  // fixed: wqb 42,467,328 | wob 14,155,776  (= 56,623,104)
  // per-bc: xb 786,432 | QKn 18,874,368 | Vt 9,437,184 | SP 6,291,456
  // aliases: P = SP in-place; H = QKn Q-section (ld 18432); Part = SP
  int bc = 0;
  for (int c = 8; c >= 1; c >>= 1)
    if (56623104UL + (unsigned long)c*35389440UL <= ws_size) { bc = c; break; }
  if (bc == 0) return;

  char* ws = (char*)d_ws;
  u16* wqb = (u16*)(ws);
  u16* wob = (u16*)(ws + 42467328L);
  u16* xb  = (u16*)(ws + 56623104L);
  long off = 56623104L + (long)bc*786432L;
  u16* QKn = (u16*)(ws + off);  off += (long)bc*18874368L;
  u16* Vt  = (u16*)(ws + off);  off += (long)bc*9437184L;
  u16* SP  = (u16*)(ws + off);
  u16* H   = QKn;                // alias: Q-section, ld 18432
  float* Part = (float*)SP;      // alias: 4 x rows_c x 768 fp32 = SP bytes

  cvt_bf16<<<dim3(D3_*HD_/4/256), dim3(256), 0, stream>>>((const float4*)w_qkv, (ushort4*)wqb, D3_*HD_/4);
  cvt_bf16<<<dim3(HD_*NHD_/4/256), dim3(256), 0, stream>>>((const float4*)w_o, (ushort4*)wob, HD_*NHD_/4);

  const int nchunks = B_ / bc;
  const int rows_c = bc * S_;
  const int zc = bc * NH_;
  const int mT = rows_c / 128;               // {4,8,16,32}
  const int mShift = __builtin_ctz(mT);
  const int zPerX = (zc % 8 == 0) ? zc / 8 : 0;

  for (int c = 0; c < nchunks; ++c) {
    const long row0 = (long)c * rows_c;

    cvt_bf16<<<dim3(rows_c*HD_/4/256), dim3(256), 0, stream>>>(
        (const float4*)(x + row0*HD_), (ushort4*)xb, rows_c*HD_/4);

    // QKV: A = xb [rows_c][768], B = wqb [27648][768]; 2-D grid, n fastest
    GP p1; p1.A = xb; p1.B = wqb;
    p1.sAb = 0; p1.sAn = 0; p1.sBb = 0; p1.sBn = 0;
    p1.o0 = QKn; p1.o2 = Vt; p1.bias = b_qkv;
    p1.mMask = mT - 1; p1.mShift = mShift; p1.zPerX = 0;
    gemm_bt<0, HD_, HD_, HD_><<<dim3(216, mT, 1), dim3(256), 0, stream>>>(p1);

    // scores: A = Q rows (natural), B = K rows (natural)
    GP p2; p2.A = QKn; p2.B = QKn + NHD_;
    p2.sAb = (long)S_*QKLD_; p2.sAn = HD_;
    p2.sBb = (long)S_*QKLD_; p2.sBn = HD_;
    p2.o0 = SP; p2.o2 = nullptr; p2.bias = nullptr;
    p2.mMask = 0; p2.mShift = 0; p2.zPerX = zPerX;
    gemm_bt<1, QKLD_, QKLD_, HD_><<<dim3(zc * 16), dim3(256), 0, stream>>>(p2);

    softmax_rows<<<dim3(zc*S_/4), dim3(256), 0, stream>>>(SP, mask + (long)c*bc*S_);

    // AV: A = P [z][q][k], B = Vt [z][h][s]; H into Q-section (ld 18432)
    GP p3; p3.A = SP; p3.B = Vt;
    p3.sAb = (long)NH_*S_*S_; p3.sAn = (long)S_*S_;
    p3.sBb = (long)NH_*S_*HD_; p3.sBn = (long)S_*HD_;
    p3.o0 = H; p3.o2 = nullptr; p3.bias = nullptr;
    p3.mMask = 0; p3.mShift = 0; p3.zPerX = zPerX;
    gemm_bt<2, S_, S_, S_><<<dim3(zc * 24), dim3(256), 0, stream>>>(p3);

    // out projection: split-K(4) partials into SP (dead), then combine + bias
    GP p4; p4.A = H; p4.B = wob;
    p4.sAb = 0; p4.sAn = NHD_/4;   // z in 0..3 -> zb=0, zn=z -> offset z*2304
    p4.sBb = 0; p4.sBn = NHD_/4;
    p4.o0 = Part; p4.o2 = nullptr; p4.bias = nullptr;
    p4.mMask = mT - 1; p4.mShift = mShift; p4.zPerX = 0;
    gemm_bt<3, QKLD_, NHD_, NHD_/4><<<dim3(24 * mT), dim3(256), 0, stream>>>(p4);

    combine_out<<<dim3(rows_c*HD_/4/256), dim3(256), 0, stream>>>(
        (const float4*)Part, b_o, (float4*)(out + row0*HD_), rows_c*HD_/4);
  }
}

// Round 12
// 520.828 us; speedup vs baseline: 1.0909x; 1.0909x over previous
//
#include <hip/hip_runtime.h>
#include <hip/hip_bf16.h>
#include <stdint.h>

#define AS1 __attribute__((address_space(1)))
#define AS3 __attribute__((address_space(3)))

typedef __attribute__((ext_vector_type(8))) __bf16 bf16x8;
typedef __attribute__((ext_vector_type(16))) float f32x16;
typedef unsigned short u16;
typedef __attribute__((ext_vector_type(8))) unsigned short u16x8;

// ---- problem sizes (fixed for this module) ----
#define B_    8
#define S_    512
#define NH_   12
#define HD_   768
#define NHD_  (NH_*HD_)     // 9216
#define D3_   (3*NHD_)      // 27648
#define QKLD_ (2*NHD_)      // 18432: natural Q|K layout leading dim
#define QK_SCALE 0.03608439182435161f   // 1/sqrt(768)

__device__ __forceinline__ u16 f2bf(float x) {
  union { float f; unsigned u; } a; a.f = x;
  unsigned r = a.u + 0x7fffu + ((a.u >> 16) & 1u);   // RNE
  return (u16)(r >> 16);
}
__device__ __forceinline__ float bf2f(u16 x) {
  union { unsigned u; float f; } a; a.u = ((unsigned)x) << 16; return a.f;
}
// packed RNE f32x2 -> bf16x2 (one VALU inst per pair)
__device__ __forceinline__ uint2 pack4(float a, float b, float c, float d) {
  uint2 r;
  asm("v_cvt_pk_bf16_f32 %0, %1, %2" : "=v"(r.x) : "v"(a), "v"(b));
  asm("v_cvt_pk_bf16_f32 %0, %1, %2" : "=v"(r.y) : "v"(c), "v"(d));
  return r;
}

__device__ __forceinline__ void gload16(const void* g, void* l) {
  // async global->LDS; LDS dest = wave-uniform base + lane*16, global src per-lane
  __builtin_amdgcn_global_load_lds((const AS1 void*)g, (AS3 void*)l, 16, 0, 0);
}

// ============================================================================
// 128x128 GEMM, 256 threads (2x2 waves), BK=64, single-buffer 32KB LDS,
// ~5 blocks/CU (round-10 structure: best measured; r11's BK=32 dbuf regressed
// via overfetch + VALU bloat).
// THIS ROUND: 32x32x16 MFMA (halves MFMA instruction count, 2382 vs 2075 TF
// rate) with operand swap: acc[mi][nj] = mfma(bv[nj], av[mi], acc) ->
// D: m = lane&31, n-quad = nj*32 + 4*(lane>>5) + 8*q + r (4 consecutive n).
// Fragments: row = base + (lane&31); logical col16 = 2*ks + (lane>>5),
// phys col16 = logical ^ (lane&7)  [= row&7; staging swizzle unchanged:
// logical c of row r at phys c^(r&7), source pre-swizzled, verified r6-r10].
// Bank check: same-slot lane pairs differ by 8 rows -> same bank, 2-way = free.
// Grid mappings (round 10, proven):
//  MODE 0: 2-D grid, n fastest (A-panel L2-hot across 216 consecutive blocks)
//  MODE 1/2: all blocks of a head z on one XCD;  MODE 3: 2 XCDs per K-chunk
// MODE 0: QKV proj -> Q|K natural [row][18432] uint2; V -> Vt (z,h,s)
// MODE 1: scores -> S bf16 [z][row][col] * QK_SCALE (uint2)
// MODE 2: AV     -> H at (zb*512+row)*18432 + zn*768 + col (uint2)
// MODE 3: out-proj split-K partial -> fp32 Part[z][row][col] (float4)
// ============================================================================
struct GP {
  const u16* A;   // + zb*sAb + zn*sAn
  const u16* B;   // + zb*sBb + zn*sBn   (C = A * B^T)
  long sAb, sAn, sBb, sBn;
  void* o0; void* o2;
  const float* bias;
  int mMask, mShift, zPerX;
};

template<int MODE, int LDA, int LDB, int KK>
__global__ __launch_bounds__(256)
void gemm_bt(GP p) {
  __shared__ __align__(16) char smem[32768];   // A tile 16KB | B tile 16KB
  const int tid  = threadIdx.x;
  const int wave = tid >> 6, lane = tid & 63;
  const int wr = wave >> 1, wc = wave & 1;     // 2x2 waves, 64x64 each

  // ---- grid mapping ----
  int m_idx, n_idx, z;
  if constexpr (MODE == 0) {
    m_idx = blockIdx.y; n_idx = blockIdx.x; z = 0;   // n fastest
  } else {
    const int bid = blockIdx.x;
    const int xcd = bid & 7, loc = bid >> 3;
    if constexpr (MODE == 1) {
      int inner;
      if (p.zPerX) { inner = loc & 15; z = xcd * p.zPerX + (loc >> 4); }
      else         { inner = bid & 15; z = bid >> 4; }
      m_idx = inner >> 2; n_idx = inner & 3;
    } else if constexpr (MODE == 2) {
      int inner;
      if (p.zPerX) { inner = loc % 24; z = xcd * p.zPerX + loc / 24; }
      else         { inner = bid % 24; z = bid / 24; }
      m_idx = inner / 6; n_idx = inner - (inner / 6) * 6;
    } else {
      m_idx = loc & p.mMask;
      n_idx = (xcd & 1) * 3 + (loc >> p.mShift);   // 0..5
      z = xcd >> 1;                                 // K-chunk 0..3
    }
  }
  const int bm0 = m_idx * 128, bn0 = n_idx * 128;
  const int zb  = z / NH_, zn = z - zb * NH_;

  const u16* A  = p.A + zb * p.sAb + zn * p.sAn;
  const u16* Bm = p.B + zb * p.sBb + zn * p.sBn;

  f32x16 acc[2][2];
#pragma unroll
  for (int i = 0; i < 2; ++i)
#pragma unroll
    for (int j = 0; j < 2; ++j)
#pragma unroll
      for (int e = 0; e < 16; ++e) acc[i][j][e] = 0.f;

  // staging with pre-swizzled source column (verified rounds 6-10)
  const int scolsw = ((lane & 7) ^ (lane >> 3)) * 8;   // elements
  const u16* gA = A  + (size_t)(bm0 + wave*8 + (lane>>3)) * LDA + scolsw;
  const u16* gB = Bm + (size_t)(bn0 + wave*8 + (lane>>3)) * LDB + scolsw;
  char* ldsA = smem;
  char* ldsB = smem + 16384;
  char* stA  = ldsA + wave*1024;
  char* stB  = ldsB + wave*1024;

  // fragment read bases: row = wX*64 + mi*32 + (lane&31), 128B rows
  const int aRowB = (wr*64 + (lane & 31)) * 128;
  const int bRowB = (wc*64 + (lane & 31)) * 128;
  const int csw   = lane & 7;
  const int hi    = lane >> 5;   // k-group

  for (int k0 = 0; k0 < KK; k0 += 64) {
#pragma unroll
    for (int i = 0; i < 4; ++i) {
      gload16(gA + (size_t)i*32*LDA, stA + i*4096);
      gload16(gB + (size_t)i*32*LDB, stB + i*4096);
    }
    gA += 64; gB += 64;
    __syncthreads();
#pragma unroll
    for (int ks = 0; ks < 4; ++ks) {
      const int cOff = ((2*ks + hi) ^ csw) << 4;   // swizzled byte col
      const bf16x8 av0 = *(const bf16x8*)(ldsA + aRowB + cOff);
      const bf16x8 av1 = *(const bf16x8*)(ldsA + aRowB + 4096 + cOff);
      const bf16x8 bv0 = *(const bf16x8*)(ldsB + bRowB + cOff);
      const bf16x8 bv1 = *(const bf16x8*)(ldsB + bRowB + 4096 + cOff);
      // swapped operands: D m = lane&31, n quad consecutive
      acc[0][0] = __builtin_amdgcn_mfma_f32_32x32x16_bf16(bv0, av0, acc[0][0], 0, 0, 0);
      acc[0][1] = __builtin_amdgcn_mfma_f32_32x32x16_bf16(bv1, av0, acc[0][1], 0, 0, 0);
      acc[1][0] = __builtin_amdgcn_mfma_f32_32x32x16_bf16(bv0, av1, acc[1][0], 0, 0, 0);
      acc[1][1] = __builtin_amdgcn_mfma_f32_32x32x16_bf16(bv1, av1, acc[1][1], 0, 0, 0);
    }
    __syncthreads();
  }

  // epilogue (swapped 32x32 layout): m = bm0+wr*64+mi*32+(lane&31)
  //   n = bn0+wc*64+nj*32+4*(lane>>5)+8*q + r   (r = reg&3, q = reg>>2)
  const int mB = bm0 + wr*64 + (lane & 31);
  const int nB = bn0 + wc*64 + (hi << 2);
#pragma unroll
  for (int mi = 0; mi < 2; ++mi) {
    const int m = mB + mi*32;
#pragma unroll
    for (int nj = 0; nj < 2; ++nj) {
#pragma unroll
      for (int q = 0; q < 4; ++q) {
        const int n = nB + nj*32 + 8*q;
        const float v0 = acc[mi][nj][4*q+0];
        const float v1 = acc[mi][nj][4*q+1];
        const float v2 = acc[mi][nj][4*q+2];
        const float v3 = acc[mi][nj][4*q+3];
        if constexpr (MODE == 0) {
          const float4 b4 = *(const float4*)(p.bias + n);
          if (bn0 < QKLD_) {
            *(uint2*)((u16*)p.o0 + (long)m * QKLD_ + n) =
                pack4(v0+b4.x, v1+b4.y, v2+b4.z, v3+b4.w);
          } else {
            const int vcol = n - QKLD_;
            const int nh = vcol / HD_;
            const int h  = vcol - nh * HD_;
            u16* vb = (u16*)p.o2 + (long)((m >> 9) * NH_ + nh) * (S_*HD_)
                      + (long)h * S_ + (m & 511);
            vb[0]    = f2bf(v0+b4.x);
            vb[512]  = f2bf(v1+b4.y);
            vb[1024] = f2bf(v2+b4.z);
            vb[1536] = f2bf(v3+b4.w);
          }
        } else if constexpr (MODE == 1) {
          *(uint2*)((u16*)p.o0 + (long)z*S_*S_ + (long)m*S_ + n) =
              pack4(v0*QK_SCALE, v1*QK_SCALE, v2*QK_SCALE, v3*QK_SCALE);
        } else if constexpr (MODE == 2) {
          *(uint2*)((u16*)p.o0 + (long)(zb*S_ + m)*QKLD_ + zn*HD_ + n) =
              pack4(v0, v1, v2, v3);
        } else {
          const long rowsTot = (long)(p.mMask + 1) * 128;
          float4 f; f.x = v0; f.y = v1; f.z = v2; f.w = v3;
          *(float4*)((float*)p.o0 + ((long)z * rowsTot + m) * HD_ + n) = f;
        }
      }
    }
  }
}

// one wave per row (512 cols, bf16, IN-PLACE): +mask, softmax
__global__ __launch_bounds__(256)
void softmax_rows(u16* __restrict__ SP, const float* __restrict__ maskc) {
  const int wave = threadIdx.x >> 6, lane = threadIdx.x & 63;
  const int rid = blockIdx.x * 4 + wave;
  const int z = rid >> 9;
  const int b = z / NH_;
  const u16x8 sv = *(const u16x8*)(SP + (size_t)rid * S_ + lane*8);
  const float* mrow = maskc + (size_t)b * S_;
  float vals[8];
  float m = -3.4e38f;
#pragma unroll
  for (int j = 0; j < 8; ++j) {
    vals[j] = bf2f(sv[j]) + mrow[lane*8 + j];
    m = fmaxf(m, vals[j]);
  }
#pragma unroll
  for (int o = 32; o > 0; o >>= 1) m = fmaxf(m, __shfl_xor(m, o));
  float sum = 0.f;
#pragma unroll
  for (int j = 0; j < 8; ++j) { vals[j] = __expf(vals[j] - m); sum += vals[j]; }
#pragma unroll
  for (int o = 32; o > 0; o >>= 1) sum += __shfl_xor(sum, o);
  const float inv = 1.0f / sum;
  u16x8 pv;
#pragma unroll
  for (int j = 0; j < 8; ++j) pv[j] = f2bf(vals[j] * inv);
  *(u16x8*)(SP + (size_t)rid * S_ + lane*8) = pv;
}

__global__ __launch_bounds__(256)
void cvt_bf16(const float4* __restrict__ in, ushort4* __restrict__ out, int n4) {
  const int i = blockIdx.x * 256 + threadIdx.x;
  if (i >= n4) return;
  const float4 v = in[i];
  ushort4 o;
  o.x = f2bf(v.x); o.y = f2bf(v.y); o.z = f2bf(v.z); o.w = f2bf(v.w);
  out[i] = o;
}

// out = sum of 4 fp32 partials + bias; n4 = rows_c*768/4 (float4 units)
__global__ __launch_bounds__(256)
void combine_out(const float4* __restrict__ part, const float* __restrict__ b,
                 float4* __restrict__ out, int n4) {
  const int i = blockIdx.x * 256 + threadIdx.x;
  if (i >= n4) return;
  const float4 a0 = part[i];
  const float4 a1 = part[i + (size_t)n4];
  const float4 a2 = part[i + (size_t)2*n4];
  const float4 a3 = part[i + (size_t)3*n4];
  const int c = (i * 4) % HD_;
  float4 o;
  o.x = a0.x + a1.x + a2.x + a3.x + b[c];
  o.y = a0.y + a1.y + a2.y + a3.y + b[c+1];
  o.z = a0.z + a1.z + a2.z + a3.z + b[c+2];
  o.w = a0.w + a1.w + a2.w + a3.w + b[c+3];
  out[i] = o;
}

extern "C" void kernel_launch(void* const* d_in, const int* in_sizes, int n_in,
                              void* d_out, int out_size, void* d_ws, size_t ws_size,
                              hipStream_t stream) {
  const float* x     = (const float*)d_in[0];
  const float* mask  = (const float*)d_in[1];
  const float* w_qkv = (const float*)d_in[2];
  const float* b_qkv = (const float*)d_in[3];
  const float* w_o   = (const float*)d_in[4];
  const float* b_o   = (const float*)d_in[5];
  float* out = (float*)d_out;

  // workspace (same footprint as rounds 2-11):
  // fixed: wqb 42,467,328 | wob 14,155,776  (= 56,623,104)
  // per-bc: xb 786,432 | QKn 18,874,368 | Vt 9,437,184 | SP 6,291,456
  // aliases: P = SP in-place; H = QKn Q-section (ld 18432); Part = SP
  int bc = 0;
  for (int c = 8; c >= 1; c >>= 1)
    if (56623104UL + (unsigned long)c*35389440UL <= ws_size) { bc = c; break; }
  if (bc == 0) return;

  char* ws = (char*)d_ws;
  u16* wqb = (u16*)(ws);
  u16* wob = (u16*)(ws + 42467328L);
  u16* xb  = (u16*)(ws + 56623104L);
  long off = 56623104L + (long)bc*786432L;
  u16* QKn = (u16*)(ws + off);  off += (long)bc*18874368L;
  u16* Vt  = (u16*)(ws + off);  off += (long)bc*9437184L;
  u16* SP  = (u16*)(ws + off);
  u16* H   = QKn;                // alias: Q-section, ld 18432
  float* Part = (float*)SP;      // alias: 4 x rows_c x 768 fp32 = SP bytes

  cvt_bf16<<<dim3(D3_*HD_/4/256), dim3(256), 0, stream>>>((const float4*)w_qkv, (ushort4*)wqb, D3_*HD_/4);
  cvt_bf16<<<dim3(HD_*NHD_/4/256), dim3(256), 0, stream>>>((const float4*)w_o, (ushort4*)wob, HD_*NHD_/4);

  const int nchunks = B_ / bc;
  const int rows_c = bc * S_;
  const int zc = bc * NH_;
  const int mT = rows_c / 128;               // {4,8,16,32}
  const int mShift = __builtin_ctz(mT);
  const int zPerX = (zc % 8 == 0) ? zc / 8 : 0;

  for (int c = 0; c < nchunks; ++c) {
    const long row0 = (long)c * rows_c;

    cvt_bf16<<<dim3(rows_c*HD_/4/256), dim3(256), 0, stream>>>(
        (const float4*)(x + row0*HD_), (ushort4*)xb, rows_c*HD_/4);

    // QKV: A = xb [rows_c][768], B = wqb [27648][768]; 2-D grid, n fastest
    GP p1; p1.A = xb; p1.B = wqb;
    p1.sAb = 0; p1.sAn = 0; p1.sBb = 0; p1.sBn = 0;
    p1.o0 = QKn; p1.o2 = Vt; p1.bias = b_qkv;
    p1.mMask = mT - 1; p1.mShift = mShift; p1.zPerX = 0;
    gemm_bt<0, HD_, HD_, HD_><<<dim3(216, mT, 1), dim3(256), 0, stream>>>(p1);

    // scores: A = Q rows (natural), B = K rows (natural)
    GP p2; p2.A = QKn; p2.B = QKn + NHD_;
    p2.sAb = (long)S_*QKLD_; p2.sAn = HD_;
    p2.sBb = (long)S_*QKLD_; p2.sBn = HD_;
    p2.o0 = SP; p2.o2 = nullptr; p2.bias = nullptr;
    p2.mMask = 0; p2.mShift = 0; p2.zPerX = zPerX;
    gemm_bt<1, QKLD_, QKLD_, HD_><<<dim3(zc * 16), dim3(256), 0, stream>>>(p2);

    softmax_rows<<<dim3(zc*S_/4), dim3(256), 0, stream>>>(SP, mask + (long)c*bc*S_);

    // AV: A = P [z][q][k], B = Vt [z][h][s]; H into Q-section (ld 18432)
    GP p3; p3.A = SP; p3.B = Vt;
    p3.sAb = (long)NH_*S_*S_; p3.sAn = (long)S_*S_;
    p3.sBb = (long)NH_*S_*HD_; p3.sBn = (long)S_*HD_;
    p3.o0 = H; p3.o2 = nullptr; p3.bias = nullptr;
    p3.mMask = 0; p3.mShift = 0; p3.zPerX = zPerX;
    gemm_bt<2, S_, S_, S_><<<dim3(zc * 24), dim3(256), 0, stream>>>(p3);

    // out projection: split-K(4) partials into SP (dead), then combine + bias
    GP p4; p4.A = H; p4.B = wob;
    p4.sAb = 0; p4.sAn = NHD_/4;   // z in 0..3 -> zb=0, zn=z -> offset z*2304
    p4.sBb = 0; p4.sBn = NHD_/4;
    p4.o0 = Part; p4.o2 = nullptr; p4.bias = nullptr;
    p4.mMask = mT - 1; p4.mShift = mShift; p4.zPerX = 0;
    gemm_bt<3, QKLD_, NHD_, NHD_/4><<<dim3(24 * mT), dim3(256), 0, stream>>>(p4);

    combine_out<<<dim3(rows_c*HD_/4/256), dim3(256), 0, stream>>>(
        (const float4*)Part, b_o, (float4*)(out + row0*HD_), rows_c*HD_/4);
  }
}

// Round 13
// 505.090 us; speedup vs baseline: 1.1249x; 1.0312x over previous
//
#include <hip/hip_runtime.h>
#include <hip/hip_bf16.h>
#include <stdint.h>

#define AS1 __attribute__((address_space(1)))
#define AS3 __attribute__((address_space(3)))

typedef __attribute__((ext_vector_type(8))) __bf16 bf16x8;
typedef __attribute__((ext_vector_type(16))) float f32x16;
typedef unsigned short u16;
typedef __attribute__((ext_vector_type(8))) unsigned short u16x8;

// ---- problem sizes (fixed for this module) ----
#define B_    8
#define S_    512
#define NH_   12
#define HD_   768
#define NHD_  (NH_*HD_)     // 9216
#define D3_   (3*NHD_)      // 27648
#define QKLD_ (2*NHD_)      // 18432: natural Q|K layout leading dim
#define QK_SCALE 0.03608439182435161f   // 1/sqrt(768)

__device__ __forceinline__ u16 f2bf(float x) {
  union { float f; unsigned u; } a; a.f = x;
  unsigned r = a.u + 0x7fffu + ((a.u >> 16) & 1u);   // RNE
  return (u16)(r >> 16);
}
__device__ __forceinline__ float bf2f(u16 x) {
  union { unsigned u; float f; } a; a.u = ((unsigned)x) << 16; return a.f;
}
// packed RNE f32x2 -> bf16x2 (one VALU inst per pair)
__device__ __forceinline__ uint2 pack4(float a, float b, float c, float d) {
  uint2 r;
  asm("v_cvt_pk_bf16_f32 %0, %1, %2" : "=v"(r.x) : "v"(a), "v"(b));
  asm("v_cvt_pk_bf16_f32 %0, %1, %2" : "=v"(r.y) : "v"(c), "v"(d));
  return r;
}

__device__ __forceinline__ void gload16(const void* g, void* l) {
  // async global->LDS; LDS dest = wave-uniform base + lane*16, global src per-lane
  __builtin_amdgcn_global_load_lds((const AS1 void*)g, (AS3 void*)l, 16, 0, 0);
}

// ============================================================================
// 128x128 GEMM, 256 threads (2x2 waves), BK=64, single-buffer 32KB LDS,
// ~5 blocks/CU; 32x32x16 MFMA operand-swapped (round 12, best).
// THIS ROUND: MODE-0 L2-aware XCD mapping. Round 12's n-fastest order spread
// the 32 same-B-panel blocks over all 8 XCDs -> per-XCD L2 refetched B panels
// (FETCH 468MB vs 49MB ideal). New map: XCD x owns n in [27x, 27x+27);
// within XCD, order = (mg outer, n mid, mi in MG8 inner) -> working set per
// phase = MG8 A-panels (<=1.6MB) + 1 B-panel (196KB), both L2-fit with reuse.
//   bid = x + 8*(mi + MG8*(n_local + 27*mg)); bijective.
// Swizzle, fragments, epilogues: identical to round 12 (verified).
// MODE 0: QKV proj -> Q|K natural [row][18432] uint2; V -> Vt (z,h,s)
// MODE 1: scores -> S bf16 [z][row][col] * QK_SCALE (uint2)
// MODE 2: AV     -> H at (zb*512+row)*18432 + zn*768 + col (uint2)
// MODE 3: out-proj split-K partial -> fp32 Part[z][row][col] (float4)
// ============================================================================
struct GP {
  const u16* A;   // + zb*sAb + zn*sAn
  const u16* B;   // + zb*sBb + zn*sBn   (C = A * B^T)
  long sAb, sAn, sBb, sBn;
  void* o0; void* o2;
  const float* bias;
  int mMask, mShift, zPerX;   // MODE0: mMask=MG8-1, mShift=log2(MG8)
};

template<int MODE, int LDA, int LDB, int KK>
__global__ __launch_bounds__(256)
void gemm_bt(GP p) {
  __shared__ __align__(16) char smem[32768];   // A tile 16KB | B tile 16KB
  const int tid  = threadIdx.x;
  const int wave = tid >> 6, lane = tid & 63;
  const int wr = wave >> 1, wc = wave & 1;     // 2x2 waves, 64x64 each

  // ---- grid mapping ----
  int m_idx, n_idx, z;
  {
    const int bid = blockIdx.x;
    const int xcd = bid & 7, loc = bid >> 3;
    if constexpr (MODE == 0) {
      // loc = mi + MG8*(n_local + 27*mg)
      const int mi = loc & p.mMask;
      const int t  = loc >> p.mShift;
      const int n_local = t % 27;
      const int mg = t / 27;
      m_idx = (mg << p.mShift) + mi;
      n_idx = xcd * 27 + n_local;
      z = 0;
    } else if constexpr (MODE == 1) {
      int inner;
      if (p.zPerX) { inner = loc & 15; z = xcd * p.zPerX + (loc >> 4); }
      else         { inner = bid & 15; z = bid >> 4; }
      m_idx = inner >> 2; n_idx = inner & 3;
    } else if constexpr (MODE == 2) {
      int inner;
      if (p.zPerX) { inner = loc % 24; z = xcd * p.zPerX + loc / 24; }
      else         { inner = bid % 24; z = bid / 24; }
      m_idx = inner / 6; n_idx = inner - (inner / 6) * 6;
    } else {
      m_idx = loc & p.mMask;
      n_idx = (xcd & 1) * 3 + (loc >> p.mShift);   // 0..5
      z = xcd >> 1;                                 // K-chunk 0..3
    }
  }
  const int bm0 = m_idx * 128, bn0 = n_idx * 128;
  const int zb  = z / NH_, zn = z - zb * NH_;

  const u16* A  = p.A + zb * p.sAb + zn * p.sAn;
  const u16* Bm = p.B + zb * p.sBb + zn * p.sBn;

  f32x16 acc[2][2];
#pragma unroll
  for (int i = 0; i < 2; ++i)
#pragma unroll
    for (int j = 0; j < 2; ++j)
#pragma unroll
      for (int e = 0; e < 16; ++e) acc[i][j][e] = 0.f;

  // staging with pre-swizzled source column (verified rounds 6-12)
  const int scolsw = ((lane & 7) ^ (lane >> 3)) * 8;   // elements
  const u16* gA = A  + (size_t)(bm0 + wave*8 + (lane>>3)) * LDA + scolsw;
  const u16* gB = Bm + (size_t)(bn0 + wave*8 + (lane>>3)) * LDB + scolsw;
  char* ldsA = smem;
  char* ldsB = smem + 16384;
  char* stA  = ldsA + wave*1024;
  char* stB  = ldsB + wave*1024;

  // fragment read bases: row = wX*64 + mi*32 + (lane&31), 128B rows
  const int aRowB = (wr*64 + (lane & 31)) * 128;
  const int bRowB = (wc*64 + (lane & 31)) * 128;
  const int csw   = lane & 7;
  const int hi    = lane >> 5;   // k-group

  for (int k0 = 0; k0 < KK; k0 += 64) {
#pragma unroll
    for (int i = 0; i < 4; ++i) {
      gload16(gA + (size_t)i*32*LDA, stA + i*4096);
      gload16(gB + (size_t)i*32*LDB, stB + i*4096);
    }
    gA += 64; gB += 64;
    __syncthreads();
#pragma unroll
    for (int ks = 0; ks < 4; ++ks) {
      const int cOff = ((2*ks + hi) ^ csw) << 4;   // swizzled byte col
      const bf16x8 av0 = *(const bf16x8*)(ldsA + aRowB + cOff);
      const bf16x8 av1 = *(const bf16x8*)(ldsA + aRowB + 4096 + cOff);
      const bf16x8 bv0 = *(const bf16x8*)(ldsB + bRowB + cOff);
      const bf16x8 bv1 = *(const bf16x8*)(ldsB + bRowB + 4096 + cOff);
      // swapped operands: D m = lane&31, n quad consecutive
      acc[0][0] = __builtin_amdgcn_mfma_f32_32x32x16_bf16(bv0, av0, acc[0][0], 0, 0, 0);
      acc[0][1] = __builtin_amdgcn_mfma_f32_32x32x16_bf16(bv1, av0, acc[0][1], 0, 0, 0);
      acc[1][0] = __builtin_amdgcn_mfma_f32_32x32x16_bf16(bv0, av1, acc[1][0], 0, 0, 0);
      acc[1][1] = __builtin_amdgcn_mfma_f32_32x32x16_bf16(bv1, av1, acc[1][1], 0, 0, 0);
    }
    __syncthreads();
  }

  // epilogue (swapped 32x32 layout): m = bm0+wr*64+mi*32+(lane&31)
  //   n = bn0+wc*64+nj*32+4*(lane>>5)+8*q + r   (r = reg&3, q = reg>>2)
  const int mB = bm0 + wr*64 + (lane & 31);
  const int nB = bn0 + wc*64 + (hi << 2);
#pragma unroll
  for (int mi = 0; mi < 2; ++mi) {
    const int m = mB + mi*32;
#pragma unroll
    for (int nj = 0; nj < 2; ++nj) {
#pragma unroll
      for (int q = 0; q < 4; ++q) {
        const int n = nB + nj*32 + 8*q;
        const float v0 = acc[mi][nj][4*q+0];
        const float v1 = acc[mi][nj][4*q+1];
        const float v2 = acc[mi][nj][4*q+2];
        const float v3 = acc[mi][nj][4*q+3];
        if constexpr (MODE == 0) {
          const float4 b4 = *(const float4*)(p.bias + n);
          if (bn0 < QKLD_) {
            *(uint2*)((u16*)p.o0 + (long)m * QKLD_ + n) =
                pack4(v0+b4.x, v1+b4.y, v2+b4.z, v3+b4.w);
          } else {
            const int vcol = n - QKLD_;
            const int nh = vcol / HD_;
            const int h  = vcol - nh * HD_;
            u16* vb = (u16*)p.o2 + (long)((m >> 9) * NH_ + nh) * (S_*HD_)
                      + (long)h * S_ + (m & 511);
            vb[0]    = f2bf(v0+b4.x);
            vb[512]  = f2bf(v1+b4.y);
            vb[1024] = f2bf(v2+b4.z);
            vb[1536] = f2bf(v3+b4.w);
          }
        } else if constexpr (MODE == 1) {
          *(uint2*)((u16*)p.o0 + (long)z*S_*S_ + (long)m*S_ + n) =
              pack4(v0*QK_SCALE, v1*QK_SCALE, v2*QK_SCALE, v3*QK_SCALE);
        } else if constexpr (MODE == 2) {
          *(uint2*)((u16*)p.o0 + (long)(zb*S_ + m)*QKLD_ + zn*HD_ + n) =
              pack4(v0, v1, v2, v3);
        } else {
          const long rowsTot = (long)(p.mMask + 1) * 128;
          float4 f; f.x = v0; f.y = v1; f.z = v2; f.w = v3;
          *(float4*)((float*)p.o0 + ((long)z * rowsTot + m) * HD_ + n) = f;
        }
      }
    }
  }
}

// one wave per row (512 cols, bf16, IN-PLACE): +mask, softmax
__global__ __launch_bounds__(256)
void softmax_rows(u16* __restrict__ SP, const float* __restrict__ maskc) {
  const int wave = threadIdx.x >> 6, lane = threadIdx.x & 63;
  const int rid = blockIdx.x * 4 + wave;
  const int z = rid >> 9;
  const int b = z / NH_;
  const u16x8 sv = *(const u16x8*)(SP + (size_t)rid * S_ + lane*8);
  const float* mrow = maskc + (size_t)b * S_;
  float vals[8];
  float m = -3.4e38f;
#pragma unroll
  for (int j = 0; j < 8; ++j) {
    vals[j] = bf2f(sv[j]) + mrow[lane*8 + j];
    m = fmaxf(m, vals[j]);
  }
#pragma unroll
  for (int o = 32; o > 0; o >>= 1) m = fmaxf(m, __shfl_xor(m, o));
  float sum = 0.f;
#pragma unroll
  for (int j = 0; j < 8; ++j) { vals[j] = __expf(vals[j] - m); sum += vals[j]; }
#pragma unroll
  for (int o = 32; o > 0; o >>= 1) sum += __shfl_xor(sum, o);
  const float inv = 1.0f / sum;
  u16x8 pv;
#pragma unroll
  for (int j = 0; j < 8; ++j) pv[j] = f2bf(vals[j] * inv);
  *(u16x8*)(SP + (size_t)rid * S_ + lane*8) = pv;
}

__global__ __launch_bounds__(256)
void cvt_bf16(const float4* __restrict__ in, ushort4* __restrict__ out, int n4) {
  const int i = blockIdx.x * 256 + threadIdx.x;
  if (i >= n4) return;
  const float4 v = in[i];
  ushort4 o;
  o.x = f2bf(v.x); o.y = f2bf(v.y); o.z = f2bf(v.z); o.w = f2bf(v.w);
  out[i] = o;
}

// out = sum of 4 fp32 partials + bias; n4 = rows_c*768/4 (float4 units)
__global__ __launch_bounds__(256)
void combine_out(const float4* __restrict__ part, const float* __restrict__ b,
                 float4* __restrict__ out, int n4) {
  const int i = blockIdx.x * 256 + threadIdx.x;
  if (i >= n4) return;
  const float4 a0 = part[i];
  const float4 a1 = part[i + (size_t)n4];
  const float4 a2 = part[i + (size_t)2*n4];
  const float4 a3 = part[i + (size_t)3*n4];
  const int c = (i * 4) % HD_;
  float4 o;
  o.x = a0.x + a1.x + a2.x + a3.x + b[c];
  o.y = a0.y + a1.y + a2.y + a3.y + b[c+1];
  o.z = a0.z + a1.z + a2.z + a3.z + b[c+2];
  o.w = a0.w + a1.w + a2.w + a3.w + b[c+3];
  out[i] = o;
}

extern "C" void kernel_launch(void* const* d_in, const int* in_sizes, int n_in,
                              void* d_out, int out_size, void* d_ws, size_t ws_size,
                              hipStream_t stream) {
  const float* x     = (const float*)d_in[0];
  const float* mask  = (const float*)d_in[1];
  const float* w_qkv = (const float*)d_in[2];
  const float* b_qkv = (const float*)d_in[3];
  const float* w_o   = (const float*)d_in[4];
  const float* b_o   = (const float*)d_in[5];
  float* out = (float*)d_out;

  // workspace (same footprint as rounds 2-12):
  // fixed: wqb 42,467,328 | wob 14,155,776  (= 56,623,104)
  // per-bc: xb 786,432 | QKn 18,874,368 | Vt 9,437,184 | SP 6,291,456
  // aliases: P = SP in-place; H = QKn Q-section (ld 18432); Part = SP
  int bc = 0;
  for (int c = 8; c >= 1; c >>= 1)
    if (56623104UL + (unsigned long)c*35389440UL <= ws_size) { bc = c; break; }
  if (bc == 0) return;

  char* ws = (char*)d_ws;
  u16* wqb = (u16*)(ws);
  u16* wob = (u16*)(ws + 42467328L);
  u16* xb  = (u16*)(ws + 56623104L);
  long off = 56623104L + (long)bc*786432L;
  u16* QKn = (u16*)(ws + off);  off += (long)bc*18874368L;
  u16* Vt  = (u16*)(ws + off);  off += (long)bc*9437184L;
  u16* SP  = (u16*)(ws + off);
  u16* H   = QKn;                // alias: Q-section, ld 18432
  float* Part = (float*)SP;      // alias: 4 x rows_c x 768 fp32 = SP bytes

  cvt_bf16<<<dim3(D3_*HD_/4/256), dim3(256), 0, stream>>>((const float4*)w_qkv, (ushort4*)wqb, D3_*HD_/4);
  cvt_bf16<<<dim3(HD_*NHD_/4/256), dim3(256), 0, stream>>>((const float4*)w_o, (ushort4*)wob, HD_*NHD_/4);

  const int nchunks = B_ / bc;
  const int rows_c = bc * S_;
  const int zc = bc * NH_;
  const int mT = rows_c / 128;               // {4,8,16,32}
  const int mShift = __builtin_ctz(mT);
  const int MG8 = (mT < 8) ? mT : 8;         // m-group size for MODE-0 map
  const int mg8Shift = __builtin_ctz(MG8);
  const int zPerX = (zc % 8 == 0) ? zc / 8 : 0;

  for (int c = 0; c < nchunks; ++c) {
    const long row0 = (long)c * rows_c;

    cvt_bf16<<<dim3(rows_c*HD_/4/256), dim3(256), 0, stream>>>(
        (const float4*)(x + row0*HD_), (ushort4*)xb, rows_c*HD_/4);

    // QKV: A = xb [rows_c][768], B = wqb [27648][768]
    // 1-D grid, L2-aware XCD map: bid = x + 8*(mi + MG8*(n_local + 27*mg))
    GP p1; p1.A = xb; p1.B = wqb;
    p1.sAb = 0; p1.sAn = 0; p1.sBb = 0; p1.sBn = 0;
    p1.o0 = QKn; p1.o2 = Vt; p1.bias = b_qkv;
    p1.mMask = MG8 - 1; p1.mShift = mg8Shift; p1.zPerX = 0;
    gemm_bt<0, HD_, HD_, HD_><<<dim3(216 * mT), dim3(256), 0, stream>>>(p1);

    // scores: A = Q rows (natural), B = K rows (natural)
    GP p2; p2.A = QKn; p2.B = QKn + NHD_;
    p2.sAb = (long)S_*QKLD_; p2.sAn = HD_;
    p2.sBb = (long)S_*QKLD_; p2.sBn = HD_;
    p2.o0 = SP; p2.o2 = nullptr; p2.bias = nullptr;
    p2.mMask = 0; p2.mShift = 0; p2.zPerX = zPerX;
    gemm_bt<1, QKLD_, QKLD_, HD_><<<dim3(zc * 16), dim3(256), 0, stream>>>(p2);

    softmax_rows<<<dim3(zc*S_/4), dim3(256), 0, stream>>>(SP, mask + (long)c*bc*S_);

    // AV: A = P [z][q][k], B = Vt [z][h][s]; H into Q-section (ld 18432)
    GP p3; p3.A = SP; p3.B = Vt;
    p3.sAb = (long)NH_*S_*S_; p3.sAn = (long)S_*S_;
    p3.sBb = (long)NH_*S_*HD_; p3.sBn = (long)S_*HD_;
    p3.o0 = H; p3.o2 = nullptr; p3.bias = nullptr;
    p3.mMask = 0; p3.mShift = 0; p3.zPerX = zPerX;
    gemm_bt<2, S_, S_, S_><<<dim3(zc * 24), dim3(256), 0, stream>>>(p3);

    // out projection: split-K(4) partials into SP (dead), then combine + bias
    GP p4; p4.A = H; p4.B = wob;
    p4.sAb = 0; p4.sAn = NHD_/4;   // z in 0..3 -> zb=0, zn=z -> offset z*2304
    p4.sBb = 0; p4.sBn = NHD_/4;
    p4.o0 = Part; p4.o2 = nullptr; p4.bias = nullptr;
    p4.mMask = mT - 1; p4.mShift = mShift; p4.zPerX = 0;
    gemm_bt<3, QKLD_, NHD_, NHD_/4><<<dim3(24 * mT), dim3(256), 0, stream>>>(p4);

    combine_out<<<dim3(rows_c*HD_/4/256), dim3(256), 0, stream>>>(
        (const float4*)Part, b_o, (float4*)(out + row0*HD_), rows_c*HD_/4);
  }
}